// Round 17
// baseline (109.269 us; speedup 1.0000x reference)
//
#include <hip/hip_runtime.h>
#include <hip/hip_bf16.h>

#define NN 646
#define FF 32768
#define HH 64
#define LL 128
#define TOT (NN*HH)          // 41344
#define OUTTOT (NN*LL)       // 82688
#define WT_STRIDE (FF + 32)  // padded bf16 row
#define KSPLIT 64
#define KSLICE (FF / KSPLIT) // 512
#define BK 32
#define NSTEP (KSLICE / BK)  // 16
#define NMT 6                // ceil(646/128)
#define NGEMM (NMT * KSPLIT) // 384

typedef float f32x4 __attribute__((ext_vector_type(4)));
typedef short short8 __attribute__((ext_vector_type(8)));

__device__ __forceinline__ unsigned short f2bf(float f) {
  __hip_bfloat16 h = __float2bfloat16(f);
  return __builtin_bit_cast(unsigned short, h);
}
__device__ __forceinline__ short8 pack8(float4 u, float4 v) {
  short8 r;
  r[0] = (short)f2bf(u.x); r[1] = (short)f2bf(u.y);
  r[2] = (short)f2bf(u.z); r[3] = (short)f2bf(u.w);
  r[4] = (short)f2bf(v.x); r[5] = (short)f2bf(v.y);
  r[6] = (short)f2bf(v.z); r[7] = (short)f2bf(v.w);
  return r;
}
__device__ __forceinline__ void gload16(const void* g, void* l) {
  __builtin_amdgcn_global_load_lds(
      (const __attribute__((address_space(1))) void*)g,
      (__attribute__((address_space(3))) void*)l, 16, 0, 0);
}
// block-level edge-dtype probe: true if int64 (all sampled hi-words zero)
__device__ __forceinline__ bool probe_i64(const int* e32, int* orr) {
  if (threadIdx.x == 0) *orr = 0;
  __syncthreads();
  if (threadIdx.x < 256 && e32[2 * threadIdx.x + 1] != 0) atomicOr(orr, 1);
  __syncthreads();
  return *orr == 0;
}

// ---- K_pre: blocks 0..80 init hcat (0 in cols 0..63, LPb in 64..127);
//      block 81 zeroes cnt + stats
__global__ __launch_bounds__(256) void k_pre(const float* __restrict__ LPb,
                                             float* __restrict__ hcat,
                                             int* __restrict__ cnt,
                                             float* __restrict__ stats) {
  if (blockIdx.x < 81) {
    int i4 = blockIdx.x * 256 + threadIdx.x;
    if (i4 * 4 < OUTTOT) {
      int n = (i4 * 4) & 127;
      f32x4 v = {0.f, 0.f, 0.f, 0.f};
      if (n & 64) v = *reinterpret_cast<const f32x4*>(LPb + (n - 64));
      *reinterpret_cast<f32x4*>(hcat + i4 * 4) = v;
    }
    return;
  }
  int t = threadIdx.x;
  for (int i = t; i < 648; i += 256) cnt[i] = 0;
  if (t < 2) stats[t] = 0.f;
}

// ---- K_init: blocks 0..511 transpose [W1|LPw] -> wt (16B stores);
//      blocks 512..575 count degrees (global atomics); block 576 = W2 colsums
__global__ __launch_bounds__(256) void k_init(const float* __restrict__ W1,
                                              const float* __restrict__ LPw,
                                              unsigned short* __restrict__ wt,
                                              const int* __restrict__ e32, int E,
                                              int* __restrict__ cnt,
                                              const float* __restrict__ W2,
                                              float* __restrict__ cs) {
  if (blockIdx.x < 512) {
    __shared__ float t[64][129];
    int k0 = blockIdx.x * 64;
    for (int idx = threadIdx.x; idx < 64 * 128; idx += 256) {
      int kk = idx >> 7, n = idx & 127;
      float v = (n < 64) ? W1[(size_t)(k0 + kk) * 64 + n]
                         : LPw[(size_t)(k0 + kk) * 64 + (n - 64)];
      t[kk][n] = v;
    }
    __syncthreads();
    for (int idx = threadIdx.x; idx < 1024; idx += 256) {
      int n = idx >> 3;
      int kc = (idx & 7) * 8;
      short8 v;
#pragma unroll
      for (int u = 0; u < 8; ++u) v[u] = (short)f2bf(t[kc + u][n]);
      *reinterpret_cast<short8*>(&wt[(size_t)n * WT_STRIDE + k0 + kc]) = v;
    }
    return;
  }
  if (blockIdx.x == 576) {  // cs[j] = sum_k W2[k][j]
    __shared__ float r2[2][128];
    int j = threadIdx.x & 127, h = threadIdx.x >> 7;
    float a = 0.f;
    for (int k = h * 32; k < h * 32 + 32; ++k) a += W2[k * LL + j];
    r2[h][j] = a;
    __syncthreads();
    if (h == 0) cs[j] = r2[0][j] + r2[1][j];
    return;
  }
  // ---- counting blocks (64 of them)
  __shared__ int orr;
  bool i64 = probe_i64(e32, &orr);
  const int* cp = i64 ? (e32 + 2 * (size_t)E) : (e32 + E);
  int st = i64 ? 2 : 1;
  int wid = (blockIdx.x - 512) * 256 + threadIdx.x;
  for (int e = wid; e < E; e += 64 * 256)
    atomicAdd(&cnt[cp[(size_t)e * st]], 1);
}

// ---- K_gemm: 128x128 M-tile, BK=32, counted-vmcnt 2-deep pipeline,
//      epilogue = atomicAdd into hcat (no partial buffer); block 384 = CSR scan
__global__ __launch_bounds__(256, 3) void k_gemm(const float* __restrict__ x,
                                                 const unsigned short* __restrict__ wt,
                                                 float* __restrict__ hcat,
                                                 const int* __restrict__ cnt, int E,
                                                 int* __restrict__ offsets,
                                                 float* __restrict__ dinv,
                                                 int* __restrict__ cursor) {
  __shared__ __align__(16) float As[2][128 * BK];            // 2 x 16 KB
  __shared__ __align__(16) unsigned short Bs[2][128 * BK];   // 2 x 8 KB

  int p = blockIdx.x;
  if (p == NGEMM) {  // ---- scan block
    __shared__ int wtot[4];
    int tid = threadIdx.x;
    int b = 3 * tid;
    int c0 = (b < NN) ? cnt[b] : 0;
    int c1 = (b + 1 < NN) ? cnt[b + 1] : 0;
    int c2 = (b + 2 < NN) ? cnt[b + 2] : 0;
    int s = c0 + c1 + c2;
    int lane = tid & 63, wv = tid >> 6;
    int run = s;
#pragma unroll
    for (int o = 1; o < 64; o <<= 1) { int v = __shfl_up(run, o); if (lane >= o) run += v; }
    if (lane == 63) wtot[wv] = run;
    __syncthreads();
    int wbase = 0;
    for (int i = 0; i < wv; ++i) wbase += wtot[i];
    int excl = wbase + run - s;
    if (b < NN)     { offsets[b]     = excl;           cursor[b]     = excl;           dinv[b]     = rsqrtf((float)(c0 + 1)); }
    if (b + 1 < NN) { offsets[b + 1] = excl + c0;      cursor[b + 1] = excl + c0;      dinv[b + 1] = rsqrtf((float)(c1 + 1)); }
    if (b + 2 < NN) { offsets[b + 2] = excl + c0 + c1; cursor[b + 2] = excl + c0 + c1; dinv[b + 2] = rsqrtf((float)(c2 + 1)); }
    if (tid == 0) offsets[NN] = E;
    return;
  }

  int xcd = p & 7, idx = p >> 3;       // 384 = 8 * 48, 48 = 8 * 6
  int ks = xcd + 8 * (idx / NMT);      // same-ks blocks share an XCD's L2
  int mt = idx % NMT;
  int tid = threadIdx.x;
  int w = tid >> 6, l = tid & 63;
  int lr = l & 15, g = l >> 4;
  int wr = w * 32;                     // wave's 32-row band within the 128-row tile
  int ksbase = ks * KSLICE;

  f32x4 z = {0.f, 0.f, 0.f, 0.f};
  f32x4 a00 = z, a01 = z, a02 = z, a03 = z, a04 = z, a05 = z, a06 = z, a07 = z;
  f32x4 a10 = z, a11 = z, a12 = z, a13 = z, a14 = z, a15 = z, a16 = z, a17 = z;

  auto STAGE = [&](int buf, int step) {
    int kb = ksbase + step * BK;
    // A tile: 128 rows x 32 f32 = 1024 16B-chunks; 4 per thread
#pragma unroll
    for (int j = 0; j < 4; ++j) {
      int pp = j * 256 + tid;
      int row = pp >> 3, cc = pp & 7;
      int c = cc ^ (row & 7);
      int rowg = mt * 128 + row; if (rowg > NN - 1) rowg = NN - 1;
      gload16(x + (size_t)rowg * FF + kb + c * 4, (char*)(&As[buf][0]) + pp * 16);
    }
    // B tile: 128 rows x 32 bf16 = 512 16B-chunks; 2 per thread
#pragma unroll
    for (int j = 0; j < 2; ++j) {
      int pp = j * 256 + tid;
      int row = pp >> 2, cc = pp & 3;
      int c = cc ^ (row & 3);
      gload16(wt + (size_t)row * WT_STRIDE + kb + c * 8,
              (char*)(&Bs[buf][0]) + pp * 16);
    }
  };

  auto COMPUTE = [&](int buf) {
    const char* Ab = (const char*)(&As[buf][0]);
    const char* Bb = (const char*)(&Bs[buf][0]);
    short8 af0, af1;
    {
      int row = wr + lr, rm = row & 7;
      float4 lo = *(const float4*)(Ab + (row * 8 + ((g * 2) ^ rm)) * 16);
      float4 hi = *(const float4*)(Ab + (row * 8 + ((g * 2 + 1) ^ rm)) * 16);
      af0 = pack8(lo, hi);
    }
    {
      int row = wr + 16 + lr, rm = row & 7;
      float4 lo = *(const float4*)(Ab + (row * 8 + ((g * 2) ^ rm)) * 16);
      float4 hi = *(const float4*)(Ab + (row * 8 + ((g * 2 + 1) ^ rm)) * 16);
      af1 = pack8(lo, hi);
    }
#define DO_NF(NF, A0, A1)                                                        \
    {                                                                            \
      int brow = NF * 16 + lr;                                                   \
      short8 bv = *(const short8*)(Bb + (brow * 4 + (g ^ (brow & 3))) * 16);     \
      A0 = __builtin_amdgcn_mfma_f32_16x16x32_bf16(af0, bv, A0, 0, 0, 0);        \
      A1 = __builtin_amdgcn_mfma_f32_16x16x32_bf16(af1, bv, A1, 0, 0, 0);        \
    }
    DO_NF(0, a00, a10) DO_NF(1, a01, a11) DO_NF(2, a02, a12) DO_NF(3, a03, a13)
    DO_NF(4, a04, a14) DO_NF(5, a05, a15) DO_NF(6, a06, a16) DO_NF(7, a07, a17)
#undef DO_NF
  };

  STAGE(0, 0);
  STAGE(1, 1);
#pragma unroll
  for (int t = 0; t < NSTEP; ++t) {
    if (t + 1 < NSTEP) {
      asm volatile("s_waitcnt vmcnt(6)" ::: "memory");  // tile t done, t+1 in flight
    } else {
      asm volatile("s_waitcnt vmcnt(0)" ::: "memory");
    }
    __builtin_amdgcn_s_barrier();
    COMPUTE(t & 1);
    if (t + 2 < NSTEP) {
      __builtin_amdgcn_s_barrier();    // all waves done reading buf before overwrite
      STAGE(t & 1, t + 2);
    }
  }

#define EPI(MF, NF, ACC)                                                         \
  {                                                                              \
    _Pragma("unroll")                                                            \
    for (int j = 0; j < 4; ++j) {                                                \
      int m = mt * 128 + wr + MF * 16 + g * 4 + j;                               \
      if (m < NN) atomicAdd(&hcat[m * LL + NF * 16 + lr], ACC[j]);               \
    }                                                                            \
  }
  EPI(0, 0, a00) EPI(0, 1, a01) EPI(0, 2, a02) EPI(0, 3, a03)
  EPI(0, 4, a04) EPI(0, 5, a05) EPI(0, 6, a06) EPI(0, 7, a07)
  EPI(1, 0, a10) EPI(1, 1, a11) EPI(1, 2, a12) EPI(1, 3, a13)
  EPI(1, 4, a14) EPI(1, 5, a15) EPI(1, 6, a16) EPI(1, 7, a17)
#undef EPI
}

// ---- K_place: CSR edge placement
__global__ __launch_bounds__(256) void k_place(const int* __restrict__ e32, int E,
                                               int* __restrict__ cursor,
                                               int* __restrict__ srcs) {
  __shared__ int orr;
  bool i64 = probe_i64(e32, &orr);
  int e = blockIdx.x * 256 + threadIdx.x;
  if (e >= E) return;
  const int* rp = e32;
  const int* cp = i64 ? (e32 + 2 * (size_t)E) : (e32 + E);
  int st = i64 ? 2 : 1;
  int r = rp[(size_t)e * st];
  int c = cp[(size_t)e * st];
  int pos = atomicAdd(&cursor[c], 1);
  srcs[pos] = r;
}

// ---- K_fuse1: GCN1 gather + residual + bias + self-loop + SiLU + LN stats
//      + sdi[c] + hwr[c] = (s_c @ W2) * dinv[c]   (LN folded out algebraically)
__global__ __launch_bounds__(256) void k_fuse1(const int* __restrict__ offs,
                                               const int* __restrict__ srcs,
                                               const float* __restrict__ dinv,
                                               const float* __restrict__ hcat,
                                               const float* __restrict__ b1,
                                               const float* __restrict__ W2,
                                               float* __restrict__ hwr,
                                               float* __restrict__ sdi,
                                               float* __restrict__ stats) {
  int c = blockIdx.x;
  int j = threadIdx.x & 63, qt = threadIdx.x >> 6;
  int o0 = offs[c], o1 = offs[c + 1];
  float acc = 0.f, sd = 0.f;
  for (int i = o0 + qt; i < o1; i += 4) {
    int r = srcs[i];
    float dr = dinv[r];
    acc += hcat[r * LL + j] * dr;
    sd += dr;
  }
  __shared__ float red[4][64];
  __shared__ float sdl[4];
  __shared__ float hnl[64];
  red[qt][j] = acc;
  if (j == 0) sdl[qt] = sd;
  __syncthreads();
  if (qt == 0) {
    float di = dinv[c];
    float gb = (red[0][j] + red[1][j] + red[2][j] + red[3][j]) * di;
    float t = hcat[c * LL + 64 + j] + b1[j] + gb + hcat[c * LL + j] * di * di;
    float s = t / (1.f + __expf(-t));
    hnl[j] = s;
    float sum = s, sq = s * s;
#pragma unroll
    for (int o = 32; o; o >>= 1) { sum += __shfl_down(sum, o); sq += __shfl_down(sq, o); }
    if (j == 0) {
      atomicAdd(&stats[0], sum);
      atomicAdd(&stats[1], sq);
      sdi[c] = sdl[0] + sdl[1] + sdl[2] + sdl[3] + di;
    }
  }
  __syncthreads();
  int j2 = threadIdx.x & 127, h = threadIdx.x >> 7;
  float a2 = 0.f;
#pragma unroll
  for (int k = h * 32; k < h * 32 + 32; ++k) a2 += hnl[k] * W2[k * LL + j2];
  __shared__ float r2[2][128];
  r2[h][j2] = a2;
  __syncthreads();
  if (h == 0) hwr[c * LL + j2] = (r2[0][j2] + r2[1][j2]) * dinv[c];
}

// ---- K_fuse2: GCN2 gather + LN constants + bias + self loop
__global__ __launch_bounds__(256) void k_fuse2(const int* __restrict__ offs,
                                               const int* __restrict__ srcs,
                                               const float* __restrict__ dinv,
                                               const float* __restrict__ hwr,
                                               const float* __restrict__ b2,
                                               const float* __restrict__ cs,
                                               const float* __restrict__ sdi,
                                               const float* __restrict__ stats,
                                               float* __restrict__ out) {
  int c = blockIdx.x;
  int j = threadIdx.x & 127, hf = threadIdx.x >> 7;
  int o0 = offs[c], o1 = offs[c + 1];
  float acc = 0.f;
  for (int i = o0 + hf; i < o1; i += 2) acc += hwr[srcs[i] * LL + j];
  __shared__ float red[2][128];
  red[hf][j] = acc;
  __syncthreads();
  if (hf == 0) {
    float mu = stats[0] * (1.f / TOT);
    float var = stats[1] * (1.f / TOT) - mu * mu;
    float rs = rsqrtf(var + 1e-5f);
    float S = red[0][j] + red[1][j] + hwr[c * LL + j];
    out[c * LL + j] = b2[j] + dinv[c] * (rs * S - rs * mu * cs[j] * sdi[c]);
  }
}

extern "C" void kernel_launch(void* const* d_in, const int* in_sizes, int n_in,
                              void* d_out, int out_size, void* d_ws, size_t ws_size,
                              hipStream_t stream) {
  const float* x   = (const float*)d_in[0];
  const int*   e32 = (const int*)d_in[1];
  const float* W1  = (const float*)d_in[2];
  const float* b1  = (const float*)d_in[3];
  const float* W2  = (const float*)d_in[4];
  const float* b2  = (const float*)d_in[5];
  const float* LPw = (const float*)d_in[6];
  const float* LPb = (const float*)d_in[7];
  int E = in_sizes[1] / 2;
  float* out = (float*)d_out;

  char* ws = (char*)d_ws;
  size_t o_wt   = 0;
  size_t o_hcat = 8396800;                 // 128*WT_STRIDE*2
  size_t o_hwr  = o_hcat + 330752;
  size_t o_dinv = o_hwr + 330752;
  size_t o_offs = o_dinv + 2816;
  size_t o_cnt  = o_offs + 2816;
  size_t o_stat = o_cnt + 2816;
  size_t o_cur  = o_stat + 256;
  size_t o_srcs = o_cur + 2816;
  size_t o_cs   = o_srcs + 165376;
  size_t o_sdi  = o_cs + 512;

  unsigned short* wt = (unsigned short*)(ws + o_wt);
  float* hcat   = (float*)(ws + o_hcat);
  float* hwr    = (float*)(ws + o_hwr);
  float* dinv   = (float*)(ws + o_dinv);
  int*   offs   = (int*)(ws + o_offs);
  int*   cnt    = (int*)(ws + o_cnt);
  float* stats  = (float*)(ws + o_stat);
  int*   cursor = (int*)(ws + o_cur);
  int*   srcs   = (int*)(ws + o_srcs);
  float* cs     = (float*)(ws + o_cs);
  float* sdi    = (float*)(ws + o_sdi);

  k_pre<<<82, 256, 0, stream>>>(LPb, hcat, cnt, stats);
  k_init<<<577, 256, 0, stream>>>(W1, LPw, wt, e32, E, cnt, W2, cs);
  k_gemm<<<NGEMM + 1, 256, 0, stream>>>(x, wt, hcat, cnt, E, offs, dinv, cursor);
  k_place<<<(E + 255) / 256, 256, 0, stream>>>(e32, E, cursor, srcs);
  k_fuse1<<<NN, 256, 0, stream>>>(offs, srcs, dinv, hcat, b1, W2, hwr, sdi, stats);
  k_fuse2<<<NN, 256, 0, stream>>>(offs, srcs, dinv, hwr, b2, cs, sdi, stats, out);
}

// Round 18
// 80.761 us; speedup vs baseline: 1.3530x; 1.3530x over previous
//
#include <hip/hip_runtime.h>
#include <hip/hip_bf16.h>

#define NN 646
#define FF 32768
#define HH 64
#define LL 128
#define TOT (NN*HH)          // 41344
#define OUTTOT (NN*LL)       // 82688
#define WT_STRIDE (FF + 32)  // padded bf16 row
#define KSPLIT 64
#define KSLICE (FF / KSPLIT) // 512
#define BK 32
#define NSTEP (KSLICE / BK)  // 16
#define NMT 6                // ceil(646/128)
#define NGEMM (NMT * KSPLIT) // 384

typedef float f32x4 __attribute__((ext_vector_type(4)));
typedef short short8 __attribute__((ext_vector_type(8)));

__device__ __forceinline__ unsigned short f2bf(float f) {
  __hip_bfloat16 h = __float2bfloat16(f);
  return __builtin_bit_cast(unsigned short, h);
}
__device__ __forceinline__ short8 pack8(float4 u, float4 v) {
  short8 r;
  r[0] = (short)f2bf(u.x); r[1] = (short)f2bf(u.y);
  r[2] = (short)f2bf(u.z); r[3] = (short)f2bf(u.w);
  r[4] = (short)f2bf(v.x); r[5] = (short)f2bf(v.y);
  r[6] = (short)f2bf(v.z); r[7] = (short)f2bf(v.w);
  return r;
}
__device__ __forceinline__ void gload16(const void* g, void* l) {
  __builtin_amdgcn_global_load_lds(
      (const __attribute__((address_space(1))) void*)g,
      (__attribute__((address_space(3))) void*)l, 16, 0, 0);
}
// block-level edge-dtype probe: true if int64 (all sampled hi-words zero)
__device__ __forceinline__ bool probe_i64(const int* e32, int* orr) {
  if (threadIdx.x == 0) *orr = 0;
  __syncthreads();
  if (threadIdx.x < 256 && e32[2 * threadIdx.x + 1] != 0) atomicOr(orr, 1);
  __syncthreads();
  return *orr == 0;
}

// ---- K_init: blocks 0..511 transpose [W1|LPw] -> wt (16B stores);
//      blocks 512..575 per-block degree histograms -> cntp[h][648] (no pre-zero);
//      block 576 = W2 column sums + stats zero
__global__ __launch_bounds__(256) void k_init(const float* __restrict__ W1,
                                              const float* __restrict__ LPw,
                                              unsigned short* __restrict__ wt,
                                              const int* __restrict__ e32, int E,
                                              int* __restrict__ cntp,
                                              const float* __restrict__ W2,
                                              float* __restrict__ cs,
                                              float* __restrict__ stats) {
  if (blockIdx.x < 512) {
    __shared__ float t[64][129];
    int k0 = blockIdx.x * 64;
    for (int idx = threadIdx.x; idx < 64 * 128; idx += 256) {
      int kk = idx >> 7, n = idx & 127;
      float v = (n < 64) ? W1[(size_t)(k0 + kk) * 64 + n]
                         : LPw[(size_t)(k0 + kk) * 64 + (n - 64)];
      t[kk][n] = v;
    }
    __syncthreads();
    for (int idx = threadIdx.x; idx < 1024; idx += 256) {
      int n = idx >> 3;
      int kc = (idx & 7) * 8;
      short8 v;
#pragma unroll
      for (int u = 0; u < 8; ++u) v[u] = (short)f2bf(t[kc + u][n]);
      *reinterpret_cast<short8*>(&wt[(size_t)n * WT_STRIDE + k0 + kc]) = v;
    }
    return;
  }
  if (blockIdx.x == 576) {  // cs[j] = sum_k W2[k][j]; zero stats
    __shared__ float r2[2][128];
    int j = threadIdx.x & 127, h = threadIdx.x >> 7;
    if (threadIdx.x < 2) stats[threadIdx.x] = 0.f;
    float a = 0.f;
    for (int k = h * 32; k < h * 32 + 32; ++k) a += W2[k * LL + j];
    r2[h][j] = a;
    __syncthreads();
    if (h == 0) cs[j] = r2[0][j] + r2[1][j];
    return;
  }
  // ---- histogram blocks (64): private LDS histogram, coalesced writeout
  __shared__ int lcnt[648];
  __shared__ int orr;
  int hb = blockIdx.x - 512;
  for (int i = threadIdx.x; i < 648; i += 256) lcnt[i] = 0;
  bool i64 = probe_i64(e32, &orr);   // includes the needed __syncthreads
  const int* cp = i64 ? (e32 + 2 * (size_t)E) : (e32 + E);
  int st = i64 ? 2 : 1;
  for (int e = hb * 256 + threadIdx.x; e < E; e += 64 * 256)
    atomicAdd(&lcnt[cp[(size_t)e * st]], 1);
  __syncthreads();
  for (int i = threadIdx.x; i < 648; i += 256) cntp[hb * 648 + i] = lcnt[i];
}

// ---- K_gemm: 128x128 M-tile, BK=32, 3-buffer single-barrier stage-early
//      pipeline (2-step lookahead, 12 loads in flight); block 384 = CSR scan
__global__ __launch_bounds__(256, 2) void k_gemm(const float* __restrict__ x,
                                                 const unsigned short* __restrict__ wt,
                                                 float* __restrict__ partial,
                                                 const int* __restrict__ cntp, int E,
                                                 int* __restrict__ offsets,
                                                 float* __restrict__ dinv,
                                                 int* __restrict__ cursor) {
  __shared__ __align__(16) float As[3][128 * BK];            // 3 x 16 KB
  __shared__ __align__(16) unsigned short Bs[3][128 * BK];   // 3 x 8 KB

  int p = blockIdx.x;
  if (p == NGEMM) {  // ---- scan block: sum histograms, scan, emit offs/dinv/cursor
    __shared__ int wtot[4];
    int tid = threadIdx.x;
    int b = 3 * tid;
    int c0 = 0, c1 = 0, c2 = 0;
    if (b < NN) {
#pragma unroll 8
      for (int h = 0; h < 64; ++h) {
        c0 += cntp[h * 648 + b];
        c1 += (b + 1 < NN) ? cntp[h * 648 + b + 1] : 0;
        c2 += (b + 2 < NN) ? cntp[h * 648 + b + 2] : 0;
      }
    }
    int s = c0 + c1 + c2;
    int lane = tid & 63, wv = tid >> 6;
    int run = s;
#pragma unroll
    for (int o = 1; o < 64; o <<= 1) { int v = __shfl_up(run, o); if (lane >= o) run += v; }
    if (lane == 63) wtot[wv] = run;
    __syncthreads();
    int wbase = 0;
    for (int i = 0; i < wv; ++i) wbase += wtot[i];
    int excl = wbase + run - s;
    if (b < NN)     { offsets[b]     = excl;           cursor[b]     = excl;           dinv[b]     = rsqrtf((float)(c0 + 1)); }
    if (b + 1 < NN) { offsets[b + 1] = excl + c0;      cursor[b + 1] = excl + c0;      dinv[b + 1] = rsqrtf((float)(c1 + 1)); }
    if (b + 2 < NN) { offsets[b + 2] = excl + c0 + c1; cursor[b + 2] = excl + c0 + c1; dinv[b + 2] = rsqrtf((float)(c2 + 1)); }
    if (tid == 0) offsets[NN] = E;
    return;
  }

  int xcd = p & 7, idx = p >> 3;       // 384 = 8 * 48, 48 = 8 * 6
  int ks = xcd + 8 * (idx / NMT);      // same-ks blocks share an XCD's L2
  int mt = idx % NMT;
  int tid = threadIdx.x;
  int w = tid >> 6, l = tid & 63;
  int lr = l & 15, g = l >> 4;
  int wr = w * 32;                     // wave's 32-row band within the 128-row tile
  int ksbase = ks * KSLICE;

  f32x4 z = {0.f, 0.f, 0.f, 0.f};
  f32x4 a00 = z, a01 = z, a02 = z, a03 = z, a04 = z, a05 = z, a06 = z, a07 = z;
  f32x4 a10 = z, a11 = z, a12 = z, a13 = z, a14 = z, a15 = z, a16 = z, a17 = z;

  auto STAGE = [&](int buf, int step) {
    int kb = ksbase + step * BK;
    // A tile: 128 rows x 32 f32 = 1024 16B-chunks; 4 per thread
#pragma unroll
    for (int j = 0; j < 4; ++j) {
      int pp = j * 256 + tid;
      int row = pp >> 3, cc = pp & 7;
      int c = cc ^ (row & 7);
      int rowg = mt * 128 + row; if (rowg > NN - 1) rowg = NN - 1;
      gload16(x + (size_t)rowg * FF + kb + c * 4, (char*)(&As[buf][0]) + pp * 16);
    }
    // B tile: 128 rows x 32 bf16 = 512 16B-chunks; 2 per thread
#pragma unroll
    for (int j = 0; j < 2; ++j) {
      int pp = j * 256 + tid;
      int row = pp >> 2, cc = pp & 3;
      int c = cc ^ (row & 3);
      gload16(wt + (size_t)row * WT_STRIDE + kb + c * 8,
              (char*)(&Bs[buf][0]) + pp * 16);
    }
  };

  auto COMPUTE = [&](int buf) {
    const char* Ab = (const char*)(&As[buf][0]);
    const char* Bb = (const char*)(&Bs[buf][0]);
    short8 af0, af1;
    {
      int row = wr + lr, rm = row & 7;
      float4 lo = *(const float4*)(Ab + (row * 8 + ((g * 2) ^ rm)) * 16);
      float4 hi = *(const float4*)(Ab + (row * 8 + ((g * 2 + 1) ^ rm)) * 16);
      af0 = pack8(lo, hi);
    }
    {
      int row = wr + 16 + lr, rm = row & 7;
      float4 lo = *(const float4*)(Ab + (row * 8 + ((g * 2) ^ rm)) * 16);
      float4 hi = *(const float4*)(Ab + (row * 8 + ((g * 2 + 1) ^ rm)) * 16);
      af1 = pack8(lo, hi);
    }
#define DO_NF(NF, A0, A1)                                                        \
    {                                                                            \
      int brow = NF * 16 + lr;                                                   \
      short8 bv = *(const short8*)(Bb + (brow * 4 + (g ^ (brow & 3))) * 16);     \
      A0 = __builtin_amdgcn_mfma_f32_16x16x32_bf16(af0, bv, A0, 0, 0, 0);        \
      A1 = __builtin_amdgcn_mfma_f32_16x16x32_bf16(af1, bv, A1, 0, 0, 0);        \
    }
    DO_NF(0, a00, a10) DO_NF(1, a01, a11) DO_NF(2, a02, a12) DO_NF(3, a03, a13)
    DO_NF(4, a04, a14) DO_NF(5, a05, a15) DO_NF(6, a06, a16) DO_NF(7, a07, a17)
#undef DO_NF
  };

  // 3-buffer, single-barrier, stage-early schedule:
  //   step t: vmcnt(6) [tile t landed; t+1 in flight] ; barrier [all waves done
  //   reading buf (t+2)%3 == (t-1)%3] ; STAGE(tile t+2 -> that buf) ; COMPUTE(t)
  STAGE(0, 0);
  STAGE(1, 1);
#pragma unroll
  for (int t = 0; t < NSTEP; ++t) {
    if (t + 1 < NSTEP) {
      asm volatile("s_waitcnt vmcnt(6)" ::: "memory");
    } else {
      asm volatile("s_waitcnt vmcnt(0)" ::: "memory");
    }
    __builtin_amdgcn_s_barrier();
    if (t + 2 < NSTEP) STAGE((t + 2) % 3, t + 2);
    COMPUTE(t % 3);
  }

  float* pp = partial + (size_t)ks * OUTTOT;
#define EPI(MF, NF, ACC)                                                         \
  {                                                                              \
    _Pragma("unroll")                                                            \
    for (int j = 0; j < 4; ++j) {                                                \
      int m = mt * 128 + wr + MF * 16 + g * 4 + j;                               \
      if (m < NN) pp[m * LL + NF * 16 + lr] = ACC[j];                            \
    }                                                                            \
  }
  EPI(0, 0, a00) EPI(0, 1, a01) EPI(0, 2, a02) EPI(0, 3, a03)
  EPI(0, 4, a04) EPI(0, 5, a05) EPI(0, 6, a06) EPI(0, 7, a07)
  EPI(1, 0, a10) EPI(1, 1, a11) EPI(1, 2, a12) EPI(1, 3, a13)
  EPI(1, 4, a14) EPI(1, 5, a15) EPI(1, 6, a16) EPI(1, 7, a17)
#undef EPI
}

// ---- K_redplace: blocks 0..80 reduce 64 partials; blocks 81..242 CSR placement
__global__ __launch_bounds__(256) void k_redplace(const float* __restrict__ partial,
                                                  const float* __restrict__ LPb,
                                                  float* __restrict__ hcat,
                                                  const int* __restrict__ e32, int E,
                                                  int* __restrict__ cursor,
                                                  int* __restrict__ srcs) {
  if (blockIdx.x < 81) {
    int i4 = blockIdx.x * 256 + threadIdx.x;
    if (i4 * 4 >= OUTTOT) return;
    f32x4 s = {0.f, 0.f, 0.f, 0.f};
#pragma unroll 8
    for (int ks = 0; ks < KSPLIT; ++ks)
      s += *reinterpret_cast<const f32x4*>(partial + (size_t)ks * OUTTOT + i4 * 4);
    int n = (i4 * 4) & 127;
    if (n & 64) s += *reinterpret_cast<const f32x4*>(LPb + (n - 64));
    *reinterpret_cast<f32x4*>(hcat + i4 * 4) = s;
    return;
  }
  __shared__ int orr;
  bool i64 = probe_i64(e32, &orr);
  int e = (blockIdx.x - 81) * 256 + threadIdx.x;
  if (e >= E) return;
  const int* rp = e32;
  const int* cp = i64 ? (e32 + 2 * (size_t)E) : (e32 + E);
  int st = i64 ? 2 : 1;
  int r = rp[(size_t)e * st];
  int c = cp[(size_t)e * st];
  int pos = atomicAdd(&cursor[c], 1);
  srcs[pos] = r;
}

// ---- K_fuse1: GCN1 gather + residual + bias + self-loop + SiLU + LN stats
//      + sdi[c] + hwr[c] = (s_c @ W2) * dinv[c]   (LN folded out algebraically)
__global__ __launch_bounds__(256) void k_fuse1(const int* __restrict__ offs,
                                               const int* __restrict__ srcs,
                                               const float* __restrict__ dinv,
                                               const float* __restrict__ hcat,
                                               const float* __restrict__ b1,
                                               const float* __restrict__ W2,
                                               float* __restrict__ hwr,
                                               float* __restrict__ sdi,
                                               float* __restrict__ stats) {
  int c = blockIdx.x;
  int j = threadIdx.x & 63, qt = threadIdx.x >> 6;
  int o0 = offs[c], o1 = offs[c + 1];
  float acc = 0.f, sd = 0.f;
  for (int i = o0 + qt; i < o1; i += 4) {
    int r = srcs[i];
    float dr = dinv[r];
    acc += hcat[r * LL + j] * dr;
    sd += dr;
  }
  __shared__ float red[4][64];
  __shared__ float sdl[4];
  __shared__ float hnl[64];
  red[qt][j] = acc;
  if (j == 0) sdl[qt] = sd;
  __syncthreads();
  if (qt == 0) {
    float di = dinv[c];
    float gb = (red[0][j] + red[1][j] + red[2][j] + red[3][j]) * di;
    float t = hcat[c * LL + 64 + j] + b1[j] + gb + hcat[c * LL + j] * di * di;
    float s = t / (1.f + __expf(-t));
    hnl[j] = s;
    float sum = s, sq = s * s;
#pragma unroll
    for (int o = 32; o; o >>= 1) { sum += __shfl_down(sum, o); sq += __shfl_down(sq, o); }
    if (j == 0) {
      atomicAdd(&stats[0], sum);
      atomicAdd(&stats[1], sq);
      sdi[c] = sdl[0] + sdl[1] + sdl[2] + sdl[3] + di;
    }
  }
  __syncthreads();
  int j2 = threadIdx.x & 127, h = threadIdx.x >> 7;
  float a2 = 0.f;
#pragma unroll
  for (int k = h * 32; k < h * 32 + 32; ++k) a2 += hnl[k] * W2[k * LL + j2];
  __shared__ float r2[2][128];
  r2[h][j2] = a2;
  __syncthreads();
  if (h == 0) hwr[c * LL + j2] = (r2[0][j2] + r2[1][j2]) * dinv[c];
}

// ---- K_fuse2: GCN2 gather + LN constants + bias + self loop
__global__ __launch_bounds__(256) void k_fuse2(const int* __restrict__ offs,
                                               const int* __restrict__ srcs,
                                               const float* __restrict__ dinv,
                                               const float* __restrict__ hwr,
                                               const float* __restrict__ b2,
                                               const float* __restrict__ cs,
                                               const float* __restrict__ sdi,
                                               const float* __restrict__ stats,
                                               float* __restrict__ out) {
  int c = blockIdx.x;
  int j = threadIdx.x & 127, hf = threadIdx.x >> 7;
  int o0 = offs[c], o1 = offs[c + 1];
  float acc = 0.f;
  for (int i = o0 + hf; i < o1; i += 2) acc += hwr[srcs[i] * LL + j];
  __shared__ float red[2][128];
  red[hf][j] = acc;
  __syncthreads();
  if (hf == 0) {
    float mu = stats[0] * (1.f / TOT);
    float var = stats[1] * (1.f / TOT) - mu * mu;
    float rs = rsqrtf(var + 1e-5f);
    float S = red[0][j] + red[1][j] + hwr[c * LL + j];
    out[c * LL + j] = b2[j] + dinv[c] * (rs * S - rs * mu * cs[j] * sdi[c]);
  }
}

extern "C" void kernel_launch(void* const* d_in, const int* in_sizes, int n_in,
                              void* d_out, int out_size, void* d_ws, size_t ws_size,
                              hipStream_t stream) {
  const float* x   = (const float*)d_in[0];
  const int*   e32 = (const int*)d_in[1];
  const float* W1  = (const float*)d_in[2];
  const float* b1  = (const float*)d_in[3];
  const float* W2  = (const float*)d_in[4];
  const float* b2  = (const float*)d_in[5];
  const float* LPw = (const float*)d_in[6];
  const float* LPb = (const float*)d_in[7];
  int E = in_sizes[1] / 2;
  float* out = (float*)d_out;

  char* ws = (char*)d_ws;
  size_t o_wt      = 0;
  size_t o_partial = 8396800;                                   // 128*WT_STRIDE*2
  size_t o_hcat    = o_partial + (size_t)KSPLIT * OUTTOT * 4;   // +21,168,128
  size_t o_hwr     = o_hcat + 330752;
  size_t o_dinv    = o_hwr + 330752;
  size_t o_offs    = o_dinv + 2816;
  size_t o_cntp    = o_offs + 2816;          // 64*648*4 = 165,888
  size_t o_stat    = o_cntp + 165888;
  size_t o_cur     = o_stat + 256;
  size_t o_srcs    = o_cur + 2816;
  size_t o_cs      = o_srcs + 165376;
  size_t o_sdi     = o_cs + 512;

  unsigned short* wt = (unsigned short*)(ws + o_wt);
  float* partial = (float*)(ws + o_partial);
  float* hcat    = (float*)(ws + o_hcat);
  float* hwr     = (float*)(ws + o_hwr);
  float* dinv    = (float*)(ws + o_dinv);
  int*   offs    = (int*)(ws + o_offs);
  int*   cntp    = (int*)(ws + o_cntp);
  float* stats   = (float*)(ws + o_stat);
  int*   cursor  = (int*)(ws + o_cur);
  int*   srcs    = (int*)(ws + o_srcs);
  float* cs      = (float*)(ws + o_cs);
  float* sdi     = (float*)(ws + o_sdi);

  k_init<<<577, 256, 0, stream>>>(W1, LPw, wt, e32, E, cntp, W2, cs, stats);
  k_gemm<<<NGEMM + 1, 256, 0, stream>>>(x, wt, partial, cntp, E, offs, dinv, cursor);
  k_redplace<<<243, 256, 0, stream>>>(partial, LPb, hcat, e32, E, cursor, srcs);
  k_fuse1<<<NN, 256, 0, stream>>>(offs, srcs, dinv, hcat, b1, W2, hwr, sdi, stats);
  k_fuse2<<<NN, 256, 0, stream>>>(offs, srcs, dinv, hwr, b2, cs, sdi, stats, out);
}